// Round 3
// baseline (290.500 us; speedup 1.0000x reference)
//
#include <hip/hip_runtime.h>

#define NR 65536
#define DIN 512
#define H 10
#define G4 40
#define EPSB 1e-5f
#define CHUNK 16                  // output steps per wave (= per chunk)
#define WPB 4                     // waves (chunks) per block
#define WARM 32                   // warm-up steps (validated: absmax ~5e-3)
#define SPW (WARM + CHUNK)        // 48 steps per wave
#define SLOTS (WARM + WPB*CHUNK)  // 96 staged steps per block
#define RPB (WPB * CHUNK)         // 64 output rows per block
#define NB1 512                   // k1 grid (wave-per-row, 32 rows/wave)
#define NB3 (NR / RPB)            // 1024 scan blocks -> 4 blocks/CU resident
#define LOG2E 1.442695041f

__device__ __forceinline__ float fast_rcp(float x) {
  return __builtin_amdgcn_rcpf(x);
}
__device__ __forceinline__ float rlane(float v, int l) {
  return __int_as_float(__builtin_amdgcn_readlane(__float_as_int(v), l));
}
// quad_perm broadcast of lane q within each aligned quad (VALU pipe, no LDS)
#define QP(v, code)                                                       \
  __int_as_float(__builtin_amdgcn_mov_dpp(__float_as_int(v), (code), 0xF, \
                                          0xF, true))
// row_ror:N within 16-lane rows (VALU pipe)
#define ROR(v, N)                                                          \
  __int_as_float(__builtin_amdgcn_mov_dpp(__float_as_int(v), 0x120 + (N), \
                                          0xF, 0xF, true))

// ---------------- K1: y = x @ W1^T + b1 (wave-per-row); partial stats -> part1
// Prefetch depth 2: loads for row i+2 in flight while computing row i.
__global__ __launch_bounds__(256) void k1_proj(const float* __restrict__ x,
                                               const float* __restrict__ W1,
                                               const float* __restrict__ b1,
                                               float* __restrict__ y,
                                               float* __restrict__ part1) {
  const int tid = threadIdx.x;
  const int lane = tid & 63;
  const int wv = tid >> 6;
  const int gw = blockIdx.x * 4 + wv;  // 0..2047

  float w[H][8];
#pragma unroll
  for (int j = 0; j < H; ++j) {
    float4 a = *(const float4*)&W1[j * DIN + lane * 8];
    float4 b = *(const float4*)&W1[j * DIN + lane * 8 + 4];
    w[j][0] = a.x; w[j][1] = a.y; w[j][2] = a.z; w[j][3] = a.w;
    w[j][4] = b.x; w[j][5] = b.y; w[j][6] = b.z; w[j][7] = b.w;
  }
  const float bj = (lane < H) ? b1[lane] : 0.0f;
  float s1 = 0.0f, s2 = 0.0f;

  const int r0 = gw * 32;
  float4 xa = *(const float4*)&x[(size_t)r0 * DIN + lane * 8];
  float4 xb = *(const float4*)&x[(size_t)r0 * DIN + lane * 8 + 4];
  float4 ya = *(const float4*)&x[(size_t)(r0 + 1) * DIN + lane * 8];
  float4 yb = *(const float4*)&x[(size_t)(r0 + 1) * DIN + lane * 8 + 4];

  for (int i = 0; i < 32; ++i) {
    const int r = r0 + i;
    const int rn = r0 + ((i + 2 < 32) ? i + 2 : 31);
    float4 za = *(const float4*)&x[(size_t)rn * DIN + lane * 8];
    float4 zb = *(const float4*)&x[(size_t)rn * DIN + lane * 8 + 4];

    float acc[H];
#pragma unroll
    for (int j = 0; j < H; ++j) {
      float s = xa.x * w[j][0];
      s = fmaf(xa.y, w[j][1], s);
      s = fmaf(xa.z, w[j][2], s);
      s = fmaf(xa.w, w[j][3], s);
      s = fmaf(xb.x, w[j][4], s);
      s = fmaf(xb.y, w[j][5], s);
      s = fmaf(xb.z, w[j][6], s);
      s = fmaf(xb.w, w[j][7], s);
      acc[j] = s;
    }
#pragma unroll
    for (int j = 0; j < H; ++j) {
      float a = acc[j];
      a += ROR(a, 1);
      a += ROR(a, 2);
      a += ROR(a, 4);
      a += ROR(a, 8);
      acc[j] = a;  // every lane now holds its 16-group sum
    }
    float tot[H];
#pragma unroll
    for (int j = 0; j < H; ++j) {
      float p0 = rlane(acc[j], 0);
      float p1 = rlane(acc[j], 16);
      float p2 = rlane(acc[j], 32);
      float p3 = rlane(acc[j], 48);
      tot[j] = (p0 + p1) + (p2 + p3);
    }
    float v = tot[0];
#pragma unroll
    for (int j = 1; j < H; ++j) v = (lane == j) ? tot[j] : v;
    if (lane < H) {
      v += bj;
      y[(size_t)r * H + lane] = v;
      s1 += v;
      s2 += v * v;
    }
    xa = ya; xb = yb;
    ya = za; yb = zb;
  }

  __shared__ float red[4][2 * H];
  if (lane < H) { red[wv][lane] = s1; red[wv][H + lane] = s2; }
  __syncthreads();
  if (tid < 2 * H) {
    float s = red[0][tid] + red[1][tid] + red[2][tid] + red[3][tid];
    part1[tid * NB1 + blockIdx.x] = s;  // plain store, no atomics
  }
}

// lane = u*4+g : unit u (0..9), gate g (0=i,1=f,2=g,3=o)
__device__ __forceinline__ void cell40(float xin, float h, float c,
                                       const float (&w)[H], float bias,
                                       float As2, float Am, float Aa,
                                       float& ht, float& ct) {
  float a0 = bias + xin, a1 = 0.0f;
#pragma unroll
  for (int m = 0; m < H; m += 2) {
    float hm0 = rlane(h, 4 * m);
    float hm1 = rlane(h, 4 * (m + 1));
    a0 = fmaf(w[m], hm0, a0);
    a1 = fmaf(w[m + 1], hm1, a1);
  }
  float a = a0 + a1;
  float e = __builtin_amdgcn_exp2f(a * As2);  // -log2e (sig) / -2log2e (tanh)
  float r = fast_rcp(1.0f + e);
  float gt = fmaf(r, Am, Aa);                 // (1,0) sig ; (2,-1) tanh
  float gi = QP(gt, 0x00);
  float gf = QP(gt, 0x55);
  float gg = QP(gt, 0xAA);
  float go = QP(gt, 0xFF);
  ct = fmaf(gf, c, gi * gg);
  float e2 = __builtin_amdgcn_exp2f(ct * (-2.0f * LOG2E));  // tanh(ct)
  float r2 = fast_rcp(1.0f + e2);
  float th = fmaf(r2, 2.0f, -1.0f);
  ht = go * th;
}

// ---------------- K3: redundant part1 reduce -> BN1 fold; per-block sxg tile
// in LDS; 48-step scan (CHUNK=16, 4 blocks/CU co-resident).
__global__ __launch_bounds__(256) void k3_scan(
    const float* __restrict__ y, const float* __restrict__ part1,
    const float* __restrict__ g1, const float* __restrict__ be1,
    const int* __restrict__ zp_arr, const int* __restrict__ broad,
    const float* __restrict__ Wih, const float* __restrict__ Whh,
    const float* __restrict__ bih, const float* __restrict__ bhh,
    float* __restrict__ outs, float* __restrict__ part2) {
  __shared__ __align__(16) float sxg[SLOTS * G4 + 64];  // +pad for lanes 40-63
  __shared__ int szb[SLOTS];
  __shared__ __align__(16) float sy[SLOTS * H];
  __shared__ float wl[G4 * H];
  __shared__ float AB[2 * H];
  __shared__ float tot[2 * H];
  __shared__ float red[WPB][2 * H];

  const int tid = threadIdx.x;
  const int blk = blockIdx.x;
  const int lane = tid & 63;
  const int wv = tid >> 6;
  const int tw = blk * RPB - WARM;  // block stage base (may be <0)

  // ---- A: redundant part1 reduction (all blocks; 40KB L2/L3-resident reads)
  for (int j = wv; j < 2 * H; j += 4) {
    float s = 0.0f;
    for (int b = lane; b < NB1; b += 64) s += part1[j * NB1 + b];
    s += ROR(s, 1); s += ROR(s, 2); s += ROR(s, 4); s += ROR(s, 8);
    float p0 = rlane(s, 0), p1 = rlane(s, 16);
    float p2 = rlane(s, 32), p3 = rlane(s, 48);
    if (lane == 0) tot[j] = (p0 + p1) + (p2 + p3);
  }
  // ---- stage y rows (contiguous window -> float4 copy), zp/bnd, Wih
  if (blk > 0) {
    const float4* src = (const float4*)(y + (size_t)tw * H);  // 16B-aligned
    for (int i = tid; i < SLOTS * H / 4; i += 256) ((float4*)sy)[i] = src[i];
  } else {
    for (int i = tid; i < SLOTS * H; i += 256) {
      const int slot = i / H;
      int t = tw + slot;
      t = t < 0 ? 0 : t;
      sy[i] = y[(size_t)t * H + (i - slot * H)];
    }
  }
  for (int i = tid; i < G4 * H; i += 256) wl[i] = Wih[i];
  for (int i = tid; i < SLOTS; i += 256) {
    const int t = tw + i;
    const int tc = t < 0 ? 0 : t;
    const int z = zp_arr[tc];
    const int bn = (t + 1 >= NR) ? 1 : ((broad[tc + 1] != broad[tc]) ? 1 : 0);
    szb[i] = z | (bn << 8);
  }
  __syncthreads();

  // ---- B: fold BN1 -> (A,B)
  if (tid < H) {
    float m = tot[tid] * (1.0f / NR);
    float v = tot[H + tid] * (1.0f / NR) - m * m;
    float inv = rsqrtf(v + EPSB);
    AB[tid] = inv * g1[tid];
    AB[H + tid] = be1[tid] - m * inv * g1[tid];
  }
  __syncthreads();

  // ---- C: per-slot gate inputs sxg (2 threads per slot, 20 dots each)
  if (tid < SLOTS * 2) {
    const int slot = tid >> 1;
    const int half = tid & 1;  // half 0: gates i,f  |  half 1: gates g,o
    float x1[H];
#pragma unroll
    for (int m = 0; m < H; ++m)
      x1[m] = fmaf(sy[slot * H + m], AB[m], AB[H + m]);
#pragma unroll
    for (int k = 0; k < H; ++k) {
      const int j0 = (half * 2) * H + k;
      const int j1 = (half * 2 + 1) * H + k;
      float s0 = 0.0f, s1 = 0.0f;
#pragma unroll
      for (int m = 0; m < H; ++m) {
        s0 = fmaf(wl[j0 * H + m], x1[m], s0);
        s1 = fmaf(wl[j1 * H + m], x1[m], s1);
      }
      *(float2*)&sxg[slot * G4 + k * 4 + half * 2] = make_float2(s0, s1);
    }
  }
  __syncthreads();

  // ---- D: wave-per-chunk scan, 40 gate-lanes, DPP quad combine
  if (lane < G4) {
    const int u = lane >> 2;
    const int g = lane & 3;

    const int row = g * H + u;  // torch gate order i,f,g,o
    float w[H];
#pragma unroll
    for (int m = 0; m < H; ++m) w[m] = Whh[row * H + m];
    const float bias = bih[row] + bhh[row];
    const bool isT = (g == 2);
    const float As2 = isT ? (-2.0f * LOG2E) : (-1.0f * LOG2E);
    const float Am = isT ? 2.0f : 1.0f;
    const float Aa = isT ? -1.0f : 0.0f;

    float h = 0.0f, c = 0.0f;
    float sh = 0.0f, sc = 0.0f, cntf = 0.0f;
    float s1 = 0.0f, s2 = 0.0f;

    const int slot0 = wv * CHUNK;
    float xv = sxg[slot0 * G4 + lane];
    int zb = szb[slot0];

    for (int s = 0; s < SPW; ++s) {
      const int slot = slot0 + s;
      const int slotn = (s + 1 < SPW) ? slot + 1 : slot;
      float xn = sxg[slotn * G4 + lane];  // prefetch next step
      int zbn = szb[slotn];

      const int t = tw + slot;
      if (t >= 0) {  // wave-uniform (false only in block 0 lead-in)
        const int zbu = __builtin_amdgcn_readfirstlane(zb);
        const int zp = zbu & 0xFF;
        for (int p = 0; p < zp; ++p) {  // wave-uniform scalar loop
          float h2, c2;
          cell40(0.0f, h, c, w, bias, As2, Am, Aa, h2, c2);
          h = h2; c = c2;
        }
        float ht, ct;
        cell40(xv, h, c, w, bias, As2, Am, Aa, ht, ct);
        sh += ht; sc += ct; cntf += 1.0f;

        if (s >= WARM) {  // output window
          if (g == 0) outs[(size_t)t * H + u] = ht;
          s1 += ht;
          s2 += ht * ht;
        }
        if (zbu & 256) {  // group boundary (wave-uniform)
          const float r = fast_rcp(cntf);
          h = sh * r; c = sc * r;
          sh = 0.0f; sc = 0.0f; cntf = 0.0f;
        }
      }
      xv = xn;
      zb = zbn;
    }
    if (g == 0) {
      red[wv][u] = s1;
      red[wv][H + u] = s2;
    }
  }
  __syncthreads();
  if (tid < 2 * H) {  // block partial -> plain store (no atomics)
    float s = red[0][tid] + red[1][tid] + red[2][tid] + red[3][tid];
    part2[tid * NB3 + blk] = s;
  }
}

// ---------------- K5: redundant part2 reduce + BN2/W2 fold, tanh head
__global__ __launch_bounds__(256) void k5_out(const float* __restrict__ part2,
                                              const float* __restrict__ g2,
                                              const float* __restrict__ be2,
                                              const float* __restrict__ W2,
                                              const float* __restrict__ b2,
                                              const float* __restrict__ outs,
                                              float* __restrict__ out) {
  __shared__ float tot[2 * H];
  __shared__ float contrib[H];
  __shared__ float cbs[H + 1];
  const int tid = threadIdx.x;
  const int lane = tid & 63;
  const int wv = tid >> 6;
  for (int j = wv; j < 2 * H; j += 4) {
    float s = 0.0f;
    for (int b = lane; b < NB3; b += 64) s += part2[j * NB3 + b];
    s += ROR(s, 1); s += ROR(s, 2); s += ROR(s, 4); s += ROR(s, 8);
    float p0 = rlane(s, 0), p1 = rlane(s, 16);
    float p2 = rlane(s, 32), p3 = rlane(s, 48);
    if (lane == 0) tot[j] = (p0 + p1) + (p2 + p3);
  }
  __syncthreads();
  if (tid < H) {
    float m = tot[tid] * (1.0f / NR);
    float v = tot[H + tid] * (1.0f / NR) - m * m;
    float inv = rsqrtf(v + EPSB);
    cbs[tid] = inv * g2[tid] * W2[tid];
    contrib[tid] = (be2[tid] - m * inv * g2[tid]) * W2[tid];
  }
  __syncthreads();
  if (tid == 0) {
    float bacc = b2[0];
#pragma unroll
    for (int j = 0; j < H; ++j) bacc += contrib[j];
    cbs[H] = bacc;
  }
  __syncthreads();
  const int t = blockIdx.x * 256 + tid;
  float s = cbs[H];
  const float* r = outs + (size_t)t * H;
#pragma unroll
  for (int j = 0; j < H; ++j) s = fmaf(r[j], cbs[j], s);
  out[t] =
      1.0f - 2.0f * fast_rcp(__builtin_amdgcn_exp2f(2.0f * LOG2E * s) + 1.0f);
}

extern "C" void kernel_launch(void* const* d_in, const int* in_sizes, int n_in,
                              void* d_out, int out_size, void* d_ws,
                              size_t ws_size, hipStream_t stream) {
  const float* x = (const float*)d_in[0];
  const int* zp = (const int*)d_in[1];
  const int* broad = (const int*)d_in[2];
  const float* W1 = (const float*)d_in[3];
  const float* b1 = (const float*)d_in[4];
  const float* g1 = (const float*)d_in[5];
  const float* be1 = (const float*)d_in[6];
  const float* Wih = (const float*)d_in[7];
  const float* Whh = (const float*)d_in[8];
  const float* bih = (const float*)d_in[9];
  const float* bhh = (const float*)d_in[10];
  const float* g2 = (const float*)d_in[11];
  const float* be2 = (const float*)d_in[12];
  const float* W2 = (const float*)d_in[13];
  const float* b2 = (const float*)d_in[14];
  float* out = (float*)d_out;

  float* ws = (float*)d_ws;
  float* part1 = ws;                        // 20*512
  float* part2 = ws + 2 * H * NB1;          // 20*1024
  float* y = part2 + 2 * H * NB3;           // N*10
  float* outs = y + (size_t)NR * H;         // N*10

  k1_proj<<<dim3(NB1), dim3(256), 0, stream>>>(x, W1, b1, y, part1);
  k3_scan<<<dim3(NB3), dim3(256), 0, stream>>>(y, part1, g1, be1, zp, broad,
                                               Wih, Whh, bih, bhh, outs,
                                               part2);
  k5_out<<<dim3(NR / 256), dim3(256), 0, stream>>>(part2, g2, be2, W2, b2,
                                                   outs, out);
  (void)in_sizes; (void)n_in; (void)out_size; (void)ws_size;
}

// Round 4
// 287.727 us; speedup vs baseline: 1.0096x; 1.0096x over previous
//
#include <hip/hip_runtime.h>

#define NR 65536
#define DIN 512
#define H 10
#define G4 40
#define EPSB 1e-5f
#define CHUNK 32                  // output steps per wave (= per chunk)
#define WPB 4                     // waves (chunks) per block
#define WARM 32                   // warm-up steps (validated: absmax ~5e-3)
#define SPW (WARM + CHUNK)        // 64 steps per wave
#define SLOTS (WARM + WPB*CHUNK)  // 160 staged steps per block
#define RPB (WPB * CHUNK)         // 128 output rows per block
#define RPW1 16                   // k1 rows per wave
#define NB1 (NR / (4 * RPW1))     // 1024 k1 blocks -> 4096 waves (latency hiding)
#define NB3 (NR / RPB)            // 512 scan blocks (measured-best geometry)
#define LOG2E 1.442695041f

__device__ __forceinline__ float fast_rcp(float x) {
  return __builtin_amdgcn_rcpf(x);
}
__device__ __forceinline__ float rlane(float v, int l) {
  return __int_as_float(__builtin_amdgcn_readlane(__float_as_int(v), l));
}
// quad_perm broadcast of lane q within each aligned quad (VALU pipe, no LDS)
#define QP(v, code)                                                       \
  __int_as_float(__builtin_amdgcn_mov_dpp(__float_as_int(v), (code), 0xF, \
                                          0xF, true))
// row_ror:N within 16-lane rows (VALU pipe)
#define ROR(v, N)                                                          \
  __int_as_float(__builtin_amdgcn_mov_dpp(__float_as_int(v), 0x120 + (N), \
                                          0xF, 0xF, true))

// ---------------- K1: y = x @ W1^T + b1 (wave-per-row, 16 rows/wave);
// partial stats -> part1.  4096 waves for latency hiding.
__global__ __launch_bounds__(256) void k1_proj(const float* __restrict__ x,
                                               const float* __restrict__ W1,
                                               const float* __restrict__ b1,
                                               float* __restrict__ y,
                                               float* __restrict__ part1) {
  const int tid = threadIdx.x;
  const int lane = tid & 63;
  const int wv = tid >> 6;
  const int gw = blockIdx.x * 4 + wv;  // 0..4095

  float w[H][8];
#pragma unroll
  for (int j = 0; j < H; ++j) {
    float4 a = *(const float4*)&W1[j * DIN + lane * 8];
    float4 b = *(const float4*)&W1[j * DIN + lane * 8 + 4];
    w[j][0] = a.x; w[j][1] = a.y; w[j][2] = a.z; w[j][3] = a.w;
    w[j][4] = b.x; w[j][5] = b.y; w[j][6] = b.z; w[j][7] = b.w;
  }
  const float bj = (lane < H) ? b1[lane] : 0.0f;
  float s1 = 0.0f, s2 = 0.0f;

  const int r0 = gw * RPW1;
  float4 xa = *(const float4*)&x[(size_t)r0 * DIN + lane * 8];
  float4 xb = *(const float4*)&x[(size_t)r0 * DIN + lane * 8 + 4];

  for (int i = 0; i < RPW1; ++i) {
    const int r = r0 + i;
    const int rn = (i + 1 < RPW1) ? r + 1 : r;
    float4 na = *(const float4*)&x[(size_t)rn * DIN + lane * 8];
    float4 nb = *(const float4*)&x[(size_t)rn * DIN + lane * 8 + 4];

    float acc[H];
#pragma unroll
    for (int j = 0; j < H; ++j) {
      float s = xa.x * w[j][0];
      s = fmaf(xa.y, w[j][1], s);
      s = fmaf(xa.z, w[j][2], s);
      s = fmaf(xa.w, w[j][3], s);
      s = fmaf(xb.x, w[j][4], s);
      s = fmaf(xb.y, w[j][5], s);
      s = fmaf(xb.z, w[j][6], s);
      s = fmaf(xb.w, w[j][7], s);
      acc[j] = s;
    }
#pragma unroll
    for (int j = 0; j < H; ++j) {
      float a = acc[j];
      a += ROR(a, 1);
      a += ROR(a, 2);
      a += ROR(a, 4);
      a += ROR(a, 8);
      acc[j] = a;  // every lane now holds its 16-group sum
    }
    float tot[H];
#pragma unroll
    for (int j = 0; j < H; ++j) {
      float p0 = rlane(acc[j], 0);
      float p1 = rlane(acc[j], 16);
      float p2 = rlane(acc[j], 32);
      float p3 = rlane(acc[j], 48);
      tot[j] = (p0 + p1) + (p2 + p3);
    }
    float v = tot[0];
#pragma unroll
    for (int j = 1; j < H; ++j) v = (lane == j) ? tot[j] : v;
    if (lane < H) {
      v += bj;
      y[(size_t)r * H + lane] = v;
      s1 += v;
      s2 += v * v;
    }
    xa = na; xb = nb;
  }

  __shared__ float red[4][2 * H];
  if (lane < H) { red[wv][lane] = s1; red[wv][H + lane] = s2; }
  __syncthreads();
  if (tid < 2 * H) {
    float s = red[0][tid] + red[1][tid] + red[2][tid] + red[3][tid];
    part1[tid * NB1 + blockIdx.x] = s;  // plain store, no atomics
  }
}

// lane = u*4+g : unit u (0..9), gate g (0=i,1=f,2=g,3=o)
__device__ __forceinline__ void cell40(float xin, float h, float c,
                                       const float (&w)[H], float bias,
                                       float As2, float Am, float Aa,
                                       float& ht, float& ct) {
  float a0 = bias + xin, a1 = 0.0f;
#pragma unroll
  for (int m = 0; m < H; m += 2) {
    float hm0 = rlane(h, 4 * m);
    float hm1 = rlane(h, 4 * (m + 1));
    a0 = fmaf(w[m], hm0, a0);
    a1 = fmaf(w[m + 1], hm1, a1);
  }
  float a = a0 + a1;
  float e = __builtin_amdgcn_exp2f(a * As2);  // -log2e (sig) / -2log2e (tanh)
  float r = fast_rcp(1.0f + e);
  float gt = fmaf(r, Am, Aa);                 // (1,0) sig ; (2,-1) tanh
  float gi = QP(gt, 0x00);
  float gf = QP(gt, 0x55);
  float gg = QP(gt, 0xAA);
  float go = QP(gt, 0xFF);
  ct = fmaf(gf, c, gi * gg);
  float e2 = __builtin_amdgcn_exp2f(ct * (-2.0f * LOG2E));  // tanh(ct)
  float r2 = fast_rcp(1.0f + e2);
  float th = fmaf(r2, 2.0f, -1.0f);
  ht = go * th;
}

// ---------------- K3: absorbs k1b (redundant part1 reduce -> BN1 fold) and
// k2 (per-block sxg tile computed in LDS from staged y rows). Scan unchanged.
__global__ __launch_bounds__(256) void k3_scan(
    const float* __restrict__ y, const float* __restrict__ part1,
    const float* __restrict__ g1, const float* __restrict__ be1,
    const int* __restrict__ zp_arr, const int* __restrict__ broad,
    const float* __restrict__ Wih, const float* __restrict__ Whh,
    const float* __restrict__ bih, const float* __restrict__ bhh,
    float* __restrict__ outs, float* __restrict__ part2) {
  __shared__ __align__(16) float sxg[SLOTS * G4 + 64];  // +pad for lanes 40-63
  __shared__ int szb[SLOTS];
  __shared__ float sy[SLOTS * H];
  __shared__ float wl[G4 * H];
  __shared__ float AB[2 * H];
  __shared__ float tot[2 * H];
  __shared__ float red[WPB][2 * H];

  const int tid = threadIdx.x;
  const int blk = blockIdx.x;
  const int lane = tid & 63;
  const int wv = tid >> 6;
  const int tw = blk * RPB - WARM;  // block stage base (may be <0)

  // ---- A: redundant part1 reduction (all blocks; 80KB L2/L3-resident reads)
  for (int j = wv; j < 2 * H; j += 4) {
    float s = 0.0f;
    for (int b = lane; b < NB1; b += 64) s += part1[j * NB1 + b];
    s += ROR(s, 1); s += ROR(s, 2); s += ROR(s, 4); s += ROR(s, 8);
    float p0 = rlane(s, 0), p1 = rlane(s, 16);
    float p2 = rlane(s, 32), p3 = rlane(s, 48);
    if (lane == 0) tot[j] = (p0 + p1) + (p2 + p3);
  }
  // ---- stage y rows, zp/bnd, Wih (concurrent with A)
  for (int i = tid; i < SLOTS * H; i += 256) {
    const int slot = i / H;
    int t = tw + slot;
    t = t < 0 ? 0 : t;
    sy[i] = y[(size_t)t * H + (i - slot * H)];
  }
  for (int i = tid; i < G4 * H; i += 256) wl[i] = Wih[i];
  for (int i = tid; i < SLOTS; i += 256) {
    const int t = tw + i;
    const int tc = t < 0 ? 0 : t;
    const int z = zp_arr[tc];
    const int bn = (t + 1 >= NR) ? 1 : ((broad[tc + 1] != broad[tc]) ? 1 : 0);
    szb[i] = z | (bn << 8);
  }
  __syncthreads();

  // ---- B: fold BN1 -> (A,B)
  if (tid < H) {
    float m = tot[tid] * (1.0f / NR);
    float v = tot[H + tid] * (1.0f / NR) - m * m;
    float inv = rsqrtf(v + EPSB);
    AB[tid] = inv * g1[tid];
    AB[H + tid] = be1[tid] - m * inv * g1[tid];
  }
  __syncthreads();

  // ---- C: per-slot gate inputs sxg (one thread per slot; old k2 math)
  if (tid < SLOTS) {
    float x1[H];
#pragma unroll
    for (int m = 0; m < H; ++m)
      x1[m] = fmaf(sy[tid * H + m], AB[m], AB[H + m]);
    float o[G4];
#pragma unroll
    for (int g = 0; g < 4; ++g) {
#pragma unroll
      for (int k = 0; k < H; ++k) {
        const int j = g * H + k;
        float s = 0.0f;
#pragma unroll
        for (int m = 0; m < H; ++m) s = fmaf(wl[j * H + m], x1[m], s);
        o[k * 4 + g] = s;
      }
    }
    float4* o4 = (float4*)&sxg[tid * G4];
#pragma unroll
    for (int q = 0; q < G4 / 4; ++q) o4[q] = ((const float4*)o)[q];
  }
  __syncthreads();

  // ---- D: wave-per-chunk scan, 40 gate-lanes, DPP quad combine
  if (lane < G4) {
    const int u = lane >> 2;
    const int g = lane & 3;

    const int row = g * H + u;  // torch gate order i,f,g,o
    float w[H];
#pragma unroll
    for (int m = 0; m < H; ++m) w[m] = Whh[row * H + m];
    const float bias = bih[row] + bhh[row];
    const bool isT = (g == 2);
    const float As2 = isT ? (-2.0f * LOG2E) : (-1.0f * LOG2E);
    const float Am = isT ? 2.0f : 1.0f;
    const float Aa = isT ? -1.0f : 0.0f;

    float h = 0.0f, c = 0.0f;
    float sh = 0.0f, sc = 0.0f, cntf = 0.0f;
    float s1 = 0.0f, s2 = 0.0f;

    const int slot0 = wv * CHUNK;
    float xv = sxg[slot0 * G4 + lane];
    int zb = szb[slot0];

    for (int s = 0; s < SPW; ++s) {
      const int slot = slot0 + s;
      const int slotn = (s + 1 < SPW) ? slot + 1 : slot;
      float xn = sxg[slotn * G4 + lane];  // prefetch next step
      int zbn = szb[slotn];

      const int t = tw + slot;
      if (t >= 0) {  // wave-uniform (false only in block 0 lead-in)
        const int zbu = __builtin_amdgcn_readfirstlane(zb);
        const int zp = zbu & 0xFF;
        for (int p = 0; p < zp; ++p) {  // wave-uniform scalar loop
          float h2, c2;
          cell40(0.0f, h, c, w, bias, As2, Am, Aa, h2, c2);
          h = h2; c = c2;
        }
        float ht, ct;
        cell40(xv, h, c, w, bias, As2, Am, Aa, ht, ct);
        sh += ht; sc += ct; cntf += 1.0f;

        if (s >= WARM) {  // output window
          if (g == 0) outs[(size_t)t * H + u] = ht;
          s1 += ht;
          s2 += ht * ht;
        }
        if (zbu & 256) {  // group boundary (wave-uniform)
          const float r = fast_rcp(cntf);
          h = sh * r; c = sc * r;
          sh = 0.0f; sc = 0.0f; cntf = 0.0f;
        }
      }
      xv = xn;
      zb = zbn;
    }
    if (g == 0) {
      red[wv][u] = s1;
      red[wv][H + u] = s2;
    }
  }
  __syncthreads();
  if (tid < 2 * H) {  // block partial -> plain store (no atomics)
    float s = red[0][tid] + red[1][tid] + red[2][tid] + red[3][tid];
    part2[tid * NB3 + blk] = s;
  }
}

// ---------------- K5: absorbs k4 (redundant part2 reduce + BN2/W2 fold), head
__global__ __launch_bounds__(256) void k5_out(const float* __restrict__ part2,
                                              const float* __restrict__ g2,
                                              const float* __restrict__ be2,
                                              const float* __restrict__ W2,
                                              const float* __restrict__ b2,
                                              const float* __restrict__ outs,
                                              float* __restrict__ out) {
  __shared__ float tot[2 * H];
  __shared__ float contrib[H];
  __shared__ float cbs[H + 1];
  const int tid = threadIdx.x;
  const int lane = tid & 63;
  const int wv = tid >> 6;
  for (int j = wv; j < 2 * H; j += 4) {
    float s = 0.0f;
    for (int b = lane; b < NB3; b += 64) s += part2[j * NB3 + b];
    s += ROR(s, 1); s += ROR(s, 2); s += ROR(s, 4); s += ROR(s, 8);
    float p0 = rlane(s, 0), p1 = rlane(s, 16);
    float p2 = rlane(s, 32), p3 = rlane(s, 48);
    if (lane == 0) tot[j] = (p0 + p1) + (p2 + p3);
  }
  __syncthreads();
  if (tid < H) {
    float m = tot[tid] * (1.0f / NR);
    float v = tot[H + tid] * (1.0f / NR) - m * m;
    float inv = rsqrtf(v + EPSB);
    cbs[tid] = inv * g2[tid] * W2[tid];
    contrib[tid] = (be2[tid] - m * inv * g2[tid]) * W2[tid];
  }
  __syncthreads();
  if (tid == 0) {
    float bacc = b2[0];
#pragma unroll
    for (int j = 0; j < H; ++j) bacc += contrib[j];
    cbs[H] = bacc;
  }
  __syncthreads();
  const int t = blockIdx.x * 256 + tid;
  float s = cbs[H];
  const float* r = outs + (size_t)t * H;
#pragma unroll
  for (int j = 0; j < H; ++j) s = fmaf(r[j], cbs[j], s);
  out[t] =
      1.0f - 2.0f * fast_rcp(__builtin_amdgcn_exp2f(2.0f * LOG2E * s) + 1.0f);
}

extern "C" void kernel_launch(void* const* d_in, const int* in_sizes, int n_in,
                              void* d_out, int out_size, void* d_ws,
                              size_t ws_size, hipStream_t stream) {
  const float* x = (const float*)d_in[0];
  const int* zp = (const int*)d_in[1];
  const int* broad = (const int*)d_in[2];
  const float* W1 = (const float*)d_in[3];
  const float* b1 = (const float*)d_in[4];
  const float* g1 = (const float*)d_in[5];
  const float* be1 = (const float*)d_in[6];
  const float* Wih = (const float*)d_in[7];
  const float* Whh = (const float*)d_in[8];
  const float* bih = (const float*)d_in[9];
  const float* bhh = (const float*)d_in[10];
  const float* g2 = (const float*)d_in[11];
  const float* be2 = (const float*)d_in[12];
  const float* W2 = (const float*)d_in[13];
  const float* b2 = (const float*)d_in[14];
  float* out = (float*)d_out;

  float* ws = (float*)d_ws;
  float* part1 = ws;                        // 20*1024
  float* part2 = ws + 2 * H * NB1;          // 20*512
  float* y = part2 + 2 * H * NB3;           // N*10
  float* outs = y + (size_t)NR * H;         // N*10

  k1_proj<<<dim3(NB1), dim3(256), 0, stream>>>(x, W1, b1, y, part1);
  k3_scan<<<dim3(NB3), dim3(256), 0, stream>>>(y, part1, g1, be1, zp, broad,
                                               Wih, Whh, bih, bhh, outs,
                                               part2);
  k5_out<<<dim3(NR / 256), dim3(256), 0, stream>>>(part2, g2, be2, W2, b2,
                                                   outs, out);
  (void)in_sizes; (void)n_in; (void)out_size; (void)ws_size;
}

// Round 5
// 273.863 us; speedup vs baseline: 1.0607x; 1.0506x over previous
//
#include <hip/hip_runtime.h>

#define NR 65536
#define DIN 512
#define H 10
#define G4 40
#define EPSB 1e-5f
#define CHUNK 32                  // output steps per wave (= per chunk)
#define WPB 4                     // waves (chunks) per block
#define WARM 32                   // warm-up steps (validated: absmax ~5e-3)
#define SPW (WARM + CHUNK)        // 64 steps per wave
#define SLOTS (WARM + WPB*CHUNK)  // 160 staged steps per block
#define NBLK (NR / (WPB * CHUNK)) // 512 blocks -> 2 waves/SIMD
#define RPB (WPB * CHUNK)         // 128 output rows per block
#define LOG2E 1.442695041f

__device__ __forceinline__ float fast_rcp(float x) {
  return __builtin_amdgcn_rcpf(x);
}
__device__ __forceinline__ float rlane(float v, int l) {
  return __int_as_float(__builtin_amdgcn_readlane(__float_as_int(v), l));
}
// quad_perm broadcast of lane q within each aligned quad (VALU pipe, no LDS)
#define QP(v, code)                                                       \
  __int_as_float(__builtin_amdgcn_mov_dpp(__float_as_int(v), (code), 0xF, \
                                          0xF, true))
// row_ror:N within 16-lane rows (VALU pipe)
#define ROR(v, N)                                                          \
  __int_as_float(__builtin_amdgcn_mov_dpp(__float_as_int(v), 0x120 + (N), \
                                          0xF, 0xF, true))

// ---------------- K1: y = x @ W1^T + b1 (wave-per-row); partial stats -> part1
__global__ __launch_bounds__(256) void k1_proj(const float* __restrict__ x,
                                               const float* __restrict__ W1,
                                               const float* __restrict__ b1,
                                               float* __restrict__ y,
                                               float* __restrict__ part1) {
  const int tid = threadIdx.x;
  const int lane = tid & 63;
  const int wv = tid >> 6;
  const int gw = blockIdx.x * 4 + wv;  // 0..2047

  float w[H][8];
#pragma unroll
  for (int j = 0; j < H; ++j) {
    float4 a = *(const float4*)&W1[j * DIN + lane * 8];
    float4 b = *(const float4*)&W1[j * DIN + lane * 8 + 4];
    w[j][0] = a.x; w[j][1] = a.y; w[j][2] = a.z; w[j][3] = a.w;
    w[j][4] = b.x; w[j][5] = b.y; w[j][6] = b.z; w[j][7] = b.w;
  }
  const float bj = (lane < H) ? b1[lane] : 0.0f;
  float s1 = 0.0f, s2 = 0.0f;

  const int r0 = gw * 32;
  float4 xa = *(const float4*)&x[(size_t)r0 * DIN + lane * 8];
  float4 xb = *(const float4*)&x[(size_t)r0 * DIN + lane * 8 + 4];

  for (int i = 0; i < 32; ++i) {
    const int r = r0 + i;
    const int rn = (i + 1 < 32) ? r + 1 : r;
    float4 na = *(const float4*)&x[(size_t)rn * DIN + lane * 8];
    float4 nb = *(const float4*)&x[(size_t)rn * DIN + lane * 8 + 4];

    float acc[H];
#pragma unroll
    for (int j = 0; j < H; ++j) {
      float s = xa.x * w[j][0];
      s = fmaf(xa.y, w[j][1], s);
      s = fmaf(xa.z, w[j][2], s);
      s = fmaf(xa.w, w[j][3], s);
      s = fmaf(xb.x, w[j][4], s);
      s = fmaf(xb.y, w[j][5], s);
      s = fmaf(xb.z, w[j][6], s);
      s = fmaf(xb.w, w[j][7], s);
      acc[j] = s;
    }
#pragma unroll
    for (int j = 0; j < H; ++j) {
      float a = acc[j];
      a += ROR(a, 1);
      a += ROR(a, 2);
      a += ROR(a, 4);
      a += ROR(a, 8);
      acc[j] = a;  // every lane now holds its 16-group sum
    }
    float tot[H];
#pragma unroll
    for (int j = 0; j < H; ++j) {
      float p0 = rlane(acc[j], 0);
      float p1 = rlane(acc[j], 16);
      float p2 = rlane(acc[j], 32);
      float p3 = rlane(acc[j], 48);
      tot[j] = (p0 + p1) + (p2 + p3);
    }
    float v = tot[0];
#pragma unroll
    for (int j = 1; j < H; ++j) v = (lane == j) ? tot[j] : v;
    if (lane < H) {
      v += bj;
      y[(size_t)r * H + lane] = v;
      s1 += v;
      s2 += v * v;
    }
    xa = na; xb = nb;
  }

  __shared__ float red[4][2 * H];
  if (lane < H) { red[wv][lane] = s1; red[wv][H + lane] = s2; }
  __syncthreads();
  if (tid < 2 * H) {
    float s = red[0][tid] + red[1][tid] + red[2][tid] + red[3][tid];
    part1[tid * NBLK + blockIdx.x] = s;  // plain store, no atomics
  }
}

// lane = u*4+g : unit u (0..9), gate g (0=i,1=f,2=g,3=o)
__device__ __forceinline__ void cell40(float xin, float h, float c,
                                       const float (&w)[H], float bias,
                                       float As2, float Am, float Aa,
                                       float& ht, float& ct) {
  float a0 = bias + xin, a1 = 0.0f;
#pragma unroll
  for (int m = 0; m < H; m += 2) {
    float hm0 = rlane(h, 4 * m);
    float hm1 = rlane(h, 4 * (m + 1));
    a0 = fmaf(w[m], hm0, a0);
    a1 = fmaf(w[m + 1], hm1, a1);
  }
  float a = a0 + a1;
  float e = __builtin_amdgcn_exp2f(a * As2);  // -log2e (sig) / -2log2e (tanh)
  float r = fast_rcp(1.0f + e);
  float gt = fmaf(r, Am, Aa);                 // (1,0) sig ; (2,-1) tanh
  float gi = QP(gt, 0x00);
  float gf = QP(gt, 0x55);
  float gg = QP(gt, 0xAA);
  float go = QP(gt, 0xFF);
  ct = fmaf(gf, c, gi * gg);
  float e2 = __builtin_amdgcn_exp2f(ct * (-2.0f * LOG2E));  // tanh(ct)
  float r2 = fast_rcp(1.0f + e2);
  float th = fmaf(r2, 2.0f, -1.0f);
  ht = go * th;
}

// ---------------- K3: absorbs k1b (redundant part1 reduce -> BN1 fold) and
// k2 (per-block sxg tile computed in LDS from staged y rows). Scan unchanged.
__global__ __launch_bounds__(256) void k3_scan(
    const float* __restrict__ y, const float* __restrict__ part1,
    const float* __restrict__ g1, const float* __restrict__ be1,
    const int* __restrict__ zp_arr, const int* __restrict__ broad,
    const float* __restrict__ Wih, const float* __restrict__ Whh,
    const float* __restrict__ bih, const float* __restrict__ bhh,
    float* __restrict__ outs, float* __restrict__ part2) {
  __shared__ __align__(16) float sxg[SLOTS * G4 + 64];  // +pad for lanes 40-63
  __shared__ int szb[SLOTS];
  __shared__ float sy[SLOTS * H];
  __shared__ float wl[G4 * H];
  __shared__ float AB[2 * H];
  __shared__ float tot[2 * H];
  __shared__ float red[WPB][2 * H];

  const int tid = threadIdx.x;
  const int blk = blockIdx.x;
  const int lane = tid & 63;
  const int wv = tid >> 6;
  const int tw = blk * RPB - WARM;  // block stage base (may be <0)

  // ---- A: redundant part1 reduction (all blocks; 40KB L2/L3-resident reads)
  for (int j = wv; j < 2 * H; j += 4) {
    float s = 0.0f;
    for (int b = lane; b < NBLK; b += 64) s += part1[j * NBLK + b];
    s += ROR(s, 1); s += ROR(s, 2); s += ROR(s, 4); s += ROR(s, 8);
    float p0 = rlane(s, 0), p1 = rlane(s, 16);
    float p2 = rlane(s, 32), p3 = rlane(s, 48);
    if (lane == 0) tot[j] = (p0 + p1) + (p2 + p3);
  }
  // ---- stage y rows, zp/bnd, Wih (concurrent with A)
  for (int i = tid; i < SLOTS * H; i += 256) {
    const int slot = i / H;
    int t = tw + slot;
    t = t < 0 ? 0 : t;
    sy[i] = y[(size_t)t * H + (i - slot * H)];
  }
  for (int i = tid; i < G4 * H; i += 256) wl[i] = Wih[i];
  for (int i = tid; i < SLOTS; i += 256) {
    const int t = tw + i;
    const int tc = t < 0 ? 0 : t;
    const int z = zp_arr[tc];
    const int bn = (t + 1 >= NR) ? 1 : ((broad[tc + 1] != broad[tc]) ? 1 : 0);
    szb[i] = z | (bn << 8);
  }
  __syncthreads();

  // ---- B: fold BN1 -> (A,B)
  if (tid < H) {
    float m = tot[tid] * (1.0f / NR);
    float v = tot[H + tid] * (1.0f / NR) - m * m;
    float inv = rsqrtf(v + EPSB);
    AB[tid] = inv * g1[tid];
    AB[H + tid] = be1[tid] - m * inv * g1[tid];
  }
  __syncthreads();

  // ---- C: per-slot gate inputs sxg (one thread per slot; old k2 math)
  if (tid < SLOTS) {
    float x1[H];
#pragma unroll
    for (int m = 0; m < H; ++m)
      x1[m] = fmaf(sy[tid * H + m], AB[m], AB[H + m]);
    float o[G4];
#pragma unroll
    for (int g = 0; g < 4; ++g) {
#pragma unroll
      for (int k = 0; k < H; ++k) {
        const int j = g * H + k;
        float s = 0.0f;
#pragma unroll
        for (int m = 0; m < H; ++m) s = fmaf(wl[j * H + m], x1[m], s);
        o[k * 4 + g] = s;
      }
    }
    float4* o4 = (float4*)&sxg[tid * G4];
#pragma unroll
    for (int q = 0; q < G4 / 4; ++q) o4[q] = ((const float4*)o)[q];
  }
  __syncthreads();

  // ---- D: wave-per-chunk scan, 40 gate-lanes, DPP quad combine
  if (lane < G4) {
    const int u = lane >> 2;
    const int g = lane & 3;

    const int row = g * H + u;  // torch gate order i,f,g,o
    float w[H];
#pragma unroll
    for (int m = 0; m < H; ++m) w[m] = Whh[row * H + m];
    const float bias = bih[row] + bhh[row];
    const bool isT = (g == 2);
    const float As2 = isT ? (-2.0f * LOG2E) : (-1.0f * LOG2E);
    const float Am = isT ? 2.0f : 1.0f;
    const float Aa = isT ? -1.0f : 0.0f;

    float h = 0.0f, c = 0.0f;
    float sh = 0.0f, sc = 0.0f, cntf = 0.0f;
    float s1 = 0.0f, s2 = 0.0f;

    const int slot0 = wv * CHUNK;
    float xv = sxg[slot0 * G4 + lane];
    int zb = szb[slot0];

    for (int s = 0; s < SPW; ++s) {
      const int slot = slot0 + s;
      const int slotn = (s + 1 < SPW) ? slot + 1 : slot;
      float xn = sxg[slotn * G4 + lane];  // prefetch next step
      int zbn = szb[slotn];

      const int t = tw + slot;
      if (t >= 0) {  // wave-uniform (false only in block 0 lead-in)
        const int zbu = __builtin_amdgcn_readfirstlane(zb);
        const int zp = zbu & 0xFF;
        for (int p = 0; p < zp; ++p) {  // wave-uniform scalar loop
          float h2, c2;
          cell40(0.0f, h, c, w, bias, As2, Am, Aa, h2, c2);
          h = h2; c = c2;
        }
        float ht, ct;
        cell40(xv, h, c, w, bias, As2, Am, Aa, ht, ct);
        sh += ht; sc += ct; cntf += 1.0f;

        if (s >= WARM) {  // output window
          if (g == 0) outs[(size_t)t * H + u] = ht;
          s1 += ht;
          s2 += ht * ht;
        }
        if (zbu & 256) {  // group boundary (wave-uniform)
          const float r = fast_rcp(cntf);
          h = sh * r; c = sc * r;
          sh = 0.0f; sc = 0.0f; cntf = 0.0f;
        }
      }
      xv = xn;
      zb = zbn;
    }
    if (g == 0) {
      red[wv][u] = s1;
      red[wv][H + u] = s2;
    }
  }
  __syncthreads();
  if (tid < 2 * H) {  // block partial -> plain store (no atomics)
    float s = red[0][tid] + red[1][tid] + red[2][tid] + red[3][tid];
    part2[tid * NBLK + blk] = s;
  }
}

// ---------------- K5: absorbs k4 (redundant part2 reduce + BN2/W2 fold), head
__global__ __launch_bounds__(256) void k5_out(const float* __restrict__ part2,
                                              const float* __restrict__ g2,
                                              const float* __restrict__ be2,
                                              const float* __restrict__ W2,
                                              const float* __restrict__ b2,
                                              const float* __restrict__ outs,
                                              float* __restrict__ out) {
  __shared__ float tot[2 * H];
  __shared__ float contrib[H];
  __shared__ float cbs[H + 1];
  const int tid = threadIdx.x;
  const int lane = tid & 63;
  const int wv = tid >> 6;
  for (int j = wv; j < 2 * H; j += 4) {
    float s = 0.0f;
    for (int b = lane; b < NBLK; b += 64) s += part2[j * NBLK + b];
    s += ROR(s, 1); s += ROR(s, 2); s += ROR(s, 4); s += ROR(s, 8);
    float p0 = rlane(s, 0), p1 = rlane(s, 16);
    float p2 = rlane(s, 32), p3 = rlane(s, 48);
    if (lane == 0) tot[j] = (p0 + p1) + (p2 + p3);
  }
  __syncthreads();
  if (tid < H) {
    float m = tot[tid] * (1.0f / NR);
    float v = tot[H + tid] * (1.0f / NR) - m * m;
    float inv = rsqrtf(v + EPSB);
    cbs[tid] = inv * g2[tid] * W2[tid];
    contrib[tid] = (be2[tid] - m * inv * g2[tid]) * W2[tid];
  }
  __syncthreads();
  if (tid == 0) {
    float bacc = b2[0];
#pragma unroll
    for (int j = 0; j < H; ++j) bacc += contrib[j];
    cbs[H] = bacc;
  }
  __syncthreads();
  const int t = blockIdx.x * 256 + tid;
  float s = cbs[H];
  const float* r = outs + (size_t)t * H;
#pragma unroll
  for (int j = 0; j < H; ++j) s = fmaf(r[j], cbs[j], s);
  out[t] =
      1.0f - 2.0f * fast_rcp(__builtin_amdgcn_exp2f(2.0f * LOG2E * s) + 1.0f);
}

extern "C" void kernel_launch(void* const* d_in, const int* in_sizes, int n_in,
                              void* d_out, int out_size, void* d_ws,
                              size_t ws_size, hipStream_t stream) {
  const float* x = (const float*)d_in[0];
  const int* zp = (const int*)d_in[1];
  const int* broad = (const int*)d_in[2];
  const float* W1 = (const float*)d_in[3];
  const float* b1 = (const float*)d_in[4];
  const float* g1 = (const float*)d_in[5];
  const float* be1 = (const float*)d_in[6];
  const float* Wih = (const float*)d_in[7];
  const float* Whh = (const float*)d_in[8];
  const float* bih = (const float*)d_in[9];
  const float* bhh = (const float*)d_in[10];
  const float* g2 = (const float*)d_in[11];
  const float* be2 = (const float*)d_in[12];
  const float* W2 = (const float*)d_in[13];
  const float* b2 = (const float*)d_in[14];
  float* out = (float*)d_out;

  float* ws = (float*)d_ws;
  float* part1 = ws;                        // 20*512
  float* part2 = ws + 2 * H * NBLK;         // 20*512
  float* y = ws + 4 * H * NBLK;             // N*10
  float* outs = y + (size_t)NR * H;         // N*10

  k1_proj<<<dim3(512), dim3(256), 0, stream>>>(x, W1, b1, y, part1);
  k3_scan<<<dim3(NBLK), dim3(256), 0, stream>>>(y, part1, g1, be1, zp, broad,
                                                Wih, Whh, bih, bhh, outs,
                                                part2);
  k5_out<<<dim3(NR / 256), dim3(256), 0, stream>>>(part2, g2, be2, W2, b2,
                                                   outs, out);
  (void)in_sizes; (void)n_in; (void)out_size; (void)ws_size;
}